// Round 5
// baseline (483.046 us; speedup 1.0000x reference)
//
#include <hip/hip_runtime.h>
#include <hip/hip_bf16.h>

// Problem constants
#define BN_TOK 2400     // B*N = 8*300
#define QDIM   256
#define NG     4
#define FLAT   32768    // G * (EOUT*POUT) = 4*8192
#define GSZ    8192
#define CT     600      // tokens per chunk
#define NCH    4        // BN_TOK / CT
#define KSP    32       // split-K ways for gemm2
#define KRANGE (FLAT / KSP)   // 1024
#define LN_EPS 1e-5f
#define PPAD   42       // row stride (ushorts) for [*][32-p] tiles: 21 dwords, odd -> conflict-free

typedef __attribute__((ext_vector_type(8))) short bf16x8;
typedef __attribute__((ext_vector_type(4))) float f32x4;
typedef __hip_bfloat16 bf16;

__device__ __forceinline__ float bf2f(ushort u) {
  union { unsigned int i; float f; } c;
  c.i = ((unsigned int)u) << 16;
  return c.f;
}
__device__ __forceinline__ ushort f2u(float f) {
  bf16 h = __float2bfloat16(f);
  union { bf16 h; ushort u; } c; c.h = h; return c.u;
}

// ---------------------------------------------------------------- fp32 -> bf16 cast
__global__ __launch_bounds__(256) void cast_k(const float* __restrict__ in,
                                              bf16* __restrict__ out, int n4) {
  int i = blockIdx.x * 256 + threadIdx.x;
  if (i < n4) {
    float4 v = ((const float4*)in)[i];
    bf16 tmp[4] = {__float2bfloat16(v.x), __float2bfloat16(v.y),
                   __float2bfloat16(v.z), __float2bfloat16(v.w)};
    ((ushort4*)out)[i] = *(const ushort4*)tmp;
  }
}

// ---------------------------------------------------------------- permuted cast of cpg_w:
// out row (g*8192 + d*64 + c) = in row (g*8192 + c*64 + d) for first 4096 of each group; rest copied.
__global__ __launch_bounds__(256) void cast_perm_k(const float* __restrict__ in,
                                                   bf16* __restrict__ out) {
  int tid = threadIdx.x;
  int orow = blockIdx.x * 8 + (tid >> 5);
  int g = orow >> 13, nl = orow & 8191;
  int srow = (nl < 4096) ? (g << 13) + ((nl & 63) << 6) + (nl >> 6) : orow;
  int col = (tid & 31) * 8;
  const float4* src = (const float4*)(in + (size_t)srow * QDIM + col);
  float4 a = src[0], b = src[1];
  bf16 tmp[8] = {__float2bfloat16(a.x), __float2bfloat16(a.y),
                 __float2bfloat16(a.z), __float2bfloat16(a.w),
                 __float2bfloat16(b.x), __float2bfloat16(b.y),
                 __float2bfloat16(b.z), __float2bfloat16(b.w)};
  *(bf16x8*)(out + (size_t)orow * QDIM + col) = *(const bf16x8*)tmp;
}

__global__ __launch_bounds__(256) void perm_bias_k(const float* __restrict__ in,
                                                   float* __restrict__ out) {
  int i = blockIdx.x * 256 + threadIdx.x;  // i < FLAT
  int g = i >> 13, nl = i & 8191;
  int src = (nl < 4096) ? (g << 13) + ((nl & 63) << 6) + (nl >> 6) : i;
  out[i] = in[src];
}

// ---------------------------------------------------------------- W = base_w + lora_B@lora_A (bf16, row-major [QDIM][FLAT])
__global__ __launch_bounds__(256) void build_wb_k(
    const float* __restrict__ base_w, const float* __restrict__ lora_A,
    const float* __restrict__ lora_B, bf16* __restrict__ Wb) {
  int jb = blockIdx.x * 256;
  int i0 = blockIdx.y * 16;
  int tid = threadIdx.x;
  __shared__ float lB[16][64];
  for (int e = tid; e < 16 * 64; e += 256)
    lB[e >> 6][e & 63] = lora_B[(size_t)(i0 + (e >> 6)) * 64 + (e & 63)];
  __syncthreads();
  int j = jb + tid;
  float acc[16] = {};
  for (int r = 0; r < 64; ++r) {
    float la = lora_A[(size_t)r * FLAT + j];
#pragma unroll
    for (int i = 0; i < 16; ++i) acc[i] += lB[i][r] * la;
  }
#pragma unroll
  for (int i = 0; i < 16; ++i)
    Wb[(size_t)(i0 + i) * FLAT + j] =
        __float2bfloat16(base_w[(size_t)(i0 + i) * FLAT + j] + acc[i]);
}

// ---------------------------------------------------------------- generic MFMA GEMM: C = A @ B^T + bias
template <bool OBF>
__global__ __launch_bounds__(256) void gemm_nt(
    const bf16* __restrict__ A, const bf16* __restrict__ B,
    const float* __restrict__ bias, void* __restrict__ Cout,
    int M, int K, int ldc) {
  __shared__ ushort As[128 * 32];
  __shared__ ushort Bs[128 * 32];
  int tid = threadIdx.x;
  int w = tid >> 6, lane = tid & 63;
  int m0 = blockIdx.x * 128;
  int n0 = blockIdx.y * 128;
  int wm = (w & 1) * 64, wn = (w >> 1) * 64;
  f32x4 acc[4][4] = {};
  for (int kb = 0; kb < K; kb += 32) {
#pragma unroll
    for (int i = 0; i < 2; ++i) {
      int chunk = (w * 2 + i) * 64 + lane;
      int row = chunk >> 2;
      int kc = (chunk & 3) * 8;
      int grow = m0 + row;
      if (grow >= M) grow = M - 1;
      const bf16* src = A + (size_t)grow * K + kb + kc;
      __builtin_amdgcn_global_load_lds(
          (const __attribute__((address_space(1))) void*)src,
          (__attribute__((address_space(3))) void*)(As + (size_t)chunk * 8), 16, 0, 0);
    }
#pragma unroll
    for (int i = 0; i < 2; ++i) {
      int chunk = (w * 2 + i) * 64 + lane;
      int row = chunk >> 2;
      int kc = (chunk & 3) * 8;
      const bf16* src = B + (size_t)(n0 + row) * K + kb + kc;
      __builtin_amdgcn_global_load_lds(
          (const __attribute__((address_space(1))) void*)src,
          (__attribute__((address_space(3))) void*)(Bs + (size_t)chunk * 8), 16, 0, 0);
    }
    __syncthreads();
    bf16x8 af[4], bfr[4];
#pragma unroll
    for (int i = 0; i < 4; ++i) {
      int r = wm + i * 16 + (lane & 15);
      af[i] = *(const bf16x8*)&As[r * 32 + (lane >> 4) * 8];
      int c = wn + i * 16 + (lane & 15);
      bfr[i] = *(const bf16x8*)&Bs[c * 32 + (lane >> 4) * 8];
    }
#pragma unroll
    for (int i = 0; i < 4; ++i)
#pragma unroll
      for (int j = 0; j < 4; ++j)
        acc[i][j] = __builtin_amdgcn_mfma_f32_16x16x32_bf16(af[i], bfr[j], acc[i][j], 0, 0, 0);
    __syncthreads();
  }
#pragma unroll
  for (int i = 0; i < 4; ++i) {
    int rb = m0 + wm + i * 16 + (lane >> 4) * 4;
#pragma unroll
    for (int j = 0; j < 4; ++j) {
      int col = n0 + wn + j * 16 + (lane & 15);
      float b = bias[col];
#pragma unroll
      for (int r = 0; r < 4; ++r) {
        if (rb + r < M) {
          float v = acc[i][j][r] + b;
          if (OBF)
            ((bf16*)Cout)[(size_t)(rb + r) * ldc + col] = __float2bfloat16(v);
          else
            ((float*)Cout)[(size_t)(rb + r) * ldc + col] = v;
        }
      }
    }
  }
}

// ---------------------------------------------------------------- chain v3: direct-fragment global reads
__device__ __forceinline__ void block_red2(float& s, float& sq, float* redS,
                                           float* redQ, int tid) {
#pragma unroll
  for (int off = 32; off > 0; off >>= 1) {
    s += __shfl_down(s, off);
    sq += __shfl_down(sq, off);
  }
  int w = tid >> 6;
  if ((tid & 63) == 0) { redS[w] = s; redQ[w] = sq; }
  __syncthreads();
  s = redS[0] + redS[1] + redS[2] + redS[3];
  sq = redQ[0] + redQ[1] + redQ[2] + redQ[3];
}

__global__ __launch_bounds__(256) void chain_k(
    const bf16* __restrict__ xb, const float* __restrict__ priv,
    const float* __restrict__ ml, const float* __restrict__ mr,
    const float* __restrict__ sl, const float* __restrict__ sr,
    bf16* __restrict__ common, int t0) {
  int tid = threadIdx.x;
  int tl = blockIdx.x;
  int g = blockIdx.y;
  int t = t0 + tl;
  int lane = tid & 63, w = tid >> 6;

  __shared__ float mzs[64], szs[64];
  __shared__ float Am[64][8];     // (ml @ mz)[c][l]
  __shared__ float Aso[128][8];   // (sl @ sz)[o][l]
  __shared__ float srs[8][32];
  __shared__ ushort o1Tb[64 * PPAD];  // o1^T [d][p] bf16
  __shared__ float redS[4], redQ[4];

  // ---- stage priv slices + sr
  if (tid < 64) mzs[tid] = priv[(size_t)t * 512 + g * 64 + tid];
  else if (tid < 128) szs[tid - 64] = priv[(size_t)t * 512 + 256 + g * 64 + (tid - 64)];
  srs[tid >> 5][tid & 31] = sr[g * 256 + tid];
  __syncthreads();

  // ---- Am[c][l], Aso[o][l]
  for (int e = tid; e < 512; e += 256) {
    int c = e >> 3, l = e & 7;
    float s = 0.f;
#pragma unroll
    for (int k = 0; k < 8; ++k) s += ml[g * 512 + c * 8 + k] * mzs[k * 8 + l];
    Am[c][l] = s;
  }
  for (int e = tid; e < 1024; e += 256) {
    int o = e >> 3, l = e & 7;
    float s = 0.f;
#pragma unroll
    for (int k = 0; k < 8; ++k) s += sl[g * 1024 + o * 8 + k] * szs[k * 8 + l];
    Aso[o][l] = s;
  }
  __syncthreads();

  bf16* cm = common + (size_t)tl * FLAT + g * GSZ;
  const ushort* cmu = (const ushort*)cm;

  // ---- A-fragments of M^T (global b128 + in-register +Am@mr), B-fragments of x
  int dlane = w * 16 + (lane & 15);
  float mrv[8];
#pragma unroll
  for (int l = 0; l < 8; ++l) mrv[l] = mr[g * 512 + l * 64 + dlane];
  bf16x8 af[2];
#pragma unroll
  for (int ks = 0; ks < 2; ++ks) {
    bf16x8 mc = *(const bf16x8*)&cmu[dlane * 64 + ks * 32 + (lane >> 4) * 8];
#pragma unroll
    for (int j = 0; j < 8; ++j) {
      int c = ks * 32 + (lane >> 4) * 8 + j;
      float mp = 0.f;
#pragma unroll
      for (int l = 0; l < 8; ++l) mp += Am[c][l] * mrv[l];
      af[ks][j] = (short)f2u(bf2f((ushort)mc[j]) + mp);
    }
  }
  const ushort* xgu = (const ushort*)(xb + ((size_t)tl * NG + g) * 2048);
  f32x4 a1[2] = {};
#pragma unroll
  for (int ks = 0; ks < 2; ++ks) {
#pragma unroll
    for (int pt = 0; pt < 2; ++pt) {
      bf16x8 bx = *(const bf16x8*)&xgu[(pt * 16 + (lane & 15)) * 64 + ks * 32 + (lane >> 4) * 8];
      a1[pt] = __builtin_amdgcn_mfma_f32_16x16x32_bf16(af[ks], bx, a1[pt], 0, 0, 0);
    }
  }
  // ---- LN1 over 2048 + relu -> o1^T bf16 in LDS
  {
    float s = 0.f, sq = 0.f;
#pragma unroll
    for (int pt = 0; pt < 2; ++pt)
#pragma unroll
      for (int r = 0; r < 4; ++r) { float v = a1[pt][r]; s += v; sq += v * v; }
    block_red2(s, sq, redS, redQ, tid);
    float mean = s * (1.f / 2048.f);
    float var = sq * (1.f / 2048.f) - mean * mean;
    float rs = rsqrtf(var + LN_EPS);
#pragma unroll
    for (int pt = 0; pt < 2; ++pt)
#pragma unroll
      for (int r = 0; r < 4; ++r) {
        float v = (a1[pt][r] - mean) * rs;
        if (v < 0.f) v = 0.f;
        int d = w * 16 + (lane >> 4) * 4 + r;
        int p = pt * 16 + (lane & 15);
        o1Tb[d * PPAD + p] = f2u(v);
      }
  }
  __syncthreads();

  // ---- out2[o][d] = sum_p S[o][p] * o1^T[d][p]; S built in-register from global Sc + Aso@sr
  f32x4 a2[2][4] = {};
  {
    bf16x8 bfd[4];
#pragma unroll
    for (int dj = 0; dj < 4; ++dj)
      bfd[dj] = *(const bf16x8*)&o1Tb[(dj * 16 + (lane & 15)) * PPAD + (lane >> 4) * 8];
#pragma unroll
    for (int oi = 0; oi < 2; ++oi) {
      int o = (2 * w + oi) * 16 + (lane & 15);
      bf16x8 sc = *(const bf16x8*)&cmu[4096 + o * 32 + (lane >> 4) * 8];
      float asv[8];
#pragma unroll
      for (int l = 0; l < 8; ++l) asv[l] = Aso[o][l];
      bf16x8 sf;
#pragma unroll
      for (int j = 0; j < 8; ++j) {
        int p = (lane >> 4) * 8 + j;
        float sp = 0.f;
#pragma unroll
        for (int l = 0; l < 8; ++l) sp += asv[l] * srs[l][p];
        sf[j] = (short)f2u(bf2f((ushort)sc[j]) + sp);
      }
#pragma unroll
      for (int dj = 0; dj < 4; ++dj)
        a2[oi][dj] = __builtin_amdgcn_mfma_f32_16x16x32_bf16(sf, bfd[dj], a2[oi][dj], 0, 0, 0);
    }
  }
  // ---- LN2 over 8192 + relu -> write bf16 in place
  {
    float s = 0.f, sq = 0.f;
#pragma unroll
    for (int oi = 0; oi < 2; ++oi)
#pragma unroll
      for (int dj = 0; dj < 4; ++dj)
#pragma unroll
        for (int r = 0; r < 4; ++r) { float v = a2[oi][dj][r]; s += v; sq += v * v; }
    block_red2(s, sq, redS, redQ, tid);
    float mean = s * (1.f / 8192.f);
    float var = sq * (1.f / 8192.f) - mean * mean;
    float rs = rsqrtf(var + LN_EPS);
#pragma unroll
    for (int oi = 0; oi < 2; ++oi)
#pragma unroll
      for (int dj = 0; dj < 4; ++dj)
#pragma unroll
        for (int r = 0; r < 4; ++r) {
          float v = (a2[oi][dj][r] - mean) * rs;
          if (v < 0.f) v = 0.f;
          int o = (2 * w + oi) * 16 + (lane >> 4) * 4 + r;
          int d = dj * 16 + (lane & 15);
          cm[o * 64 + d] = __float2bfloat16(v);
        }
  }
}

// ---------------------------------------------------------------- GEMM2 (MFMA split-K)
__global__ __launch_bounds__(256) void gemm2_mfma(
    const bf16* __restrict__ o2b, const bf16* __restrict__ Wb,
    float* __restrict__ partial) {
  __shared__ ushort As[128 * 32];
  __shared__ ushort Bs[128 * 32];
  int tid = threadIdx.x;
  int w = tid >> 6, lane = tid & 63;
  int m0 = blockIdx.x * 128;
  int n0 = blockIdx.y * 128;
  int kz = blockIdx.z;
  int wm = (w & 1) * 64, wn = (w >> 1) * 64;
  f32x4 acc[4][4] = {};
  for (int kb = kz * KRANGE; kb < (kz + 1) * KRANGE; kb += 32) {
#pragma unroll
    for (int i = 0; i < 2; ++i) {
      int chunk = (w * 2 + i) * 64 + lane;
      int row = chunk >> 2;
      int kc = (chunk & 3) * 8;
      int grow = m0 + row;
      if (grow >= CT) grow = CT - 1;
      const bf16* src = o2b + (size_t)grow * FLAT + kb + kc;
      __builtin_amdgcn_global_load_lds(
          (const __attribute__((address_space(1))) void*)src,
          (__attribute__((address_space(3))) void*)(As + (size_t)chunk * 8), 16, 0, 0);
    }
#pragma unroll
    for (int i = 0; i < 2; ++i) {
      int chunk = (w * 2 + i) * 64 + lane;
      int row = chunk >> 2;
      int kc = (chunk & 3) * 8;
      const bf16* src = Wb + (size_t)(n0 + row) * FLAT + kb + kc;
      __builtin_amdgcn_global_load_lds(
          (const __attribute__((address_space(1))) void*)src,
          (__attribute__((address_space(3))) void*)(Bs + (size_t)chunk * 8), 16, 0, 0);
    }
    __syncthreads();
    bf16x8 af[4], bfr[4];
#pragma unroll
    for (int i = 0; i < 4; ++i) {
      int r = wm + i * 16 + (lane & 15);
      af[i] = *(const bf16x8*)&As[r * 32 + (lane >> 4) * 8];
      int c = wn + i * 16 + (lane & 15);
      bfr[i] = *(const bf16x8*)&Bs[c * 32 + (lane >> 4) * 8];
    }
#pragma unroll
    for (int i = 0; i < 4; ++i)
#pragma unroll
      for (int j = 0; j < 4; ++j)
        acc[i][j] = __builtin_amdgcn_mfma_f32_16x16x32_bf16(af[i], bfr[j], acc[i][j], 0, 0, 0);
    __syncthreads();
  }
#pragma unroll
  for (int i = 0; i < 4; ++i) {
    int rb = m0 + wm + i * 16 + (lane >> 4) * 4;
#pragma unroll
    for (int j = 0; j < 4; ++j) {
      int col = n0 + wn + j * 16 + (lane & 15);
#pragma unroll
      for (int r = 0; r < 4; ++r)
        if (rb + r < CT)
          partial[((size_t)kz * CT + rb + r) * QDIM + col] = acc[i][j][r];
    }
  }
}

// ---------------------------------------------------------------- finish
__global__ __launch_bounds__(256) void finish_k(
    const float* __restrict__ partial, const float* __restrict__ query,
    const float* __restrict__ out_bias, const float* __restrict__ gamma,
    const float* __restrict__ beta, float* __restrict__ out, int t0) {
  int tid = threadIdx.x;
  int tl = blockIdx.x;
  int t = t0 + tl;
  __shared__ float redS[4], redQ[4];
  float s = 0.f;
  for (int ks = 0; ks < KSP; ++ks)
    s += partial[((size_t)ks * CT + tl) * QDIM + tid];
  float v = s + out_bias[tid] + query[(size_t)t * QDIM + tid];
  float sum = v, sqv = v * v;
  block_red2(sum, sqv, redS, redQ, tid);
  float mean = sum * (1.f / 256.f);
  float var = sqv * (1.f / 256.f) - mean * mean;
  out[(size_t)t * QDIM + tid] =
      (v - mean) * rsqrtf(var + LN_EPS) * gamma[tid] + beta[tid];
}

// ---------------------------------------------------------------- launch
extern "C" void kernel_launch(void* const* d_in, const int* in_sizes, int n_in,
                              void* d_out, int out_size, void* d_ws, size_t ws_size,
                              hipStream_t stream) {
  const float* x       = (const float*)d_in[1];
  const float* query   = (const float*)d_in[2];
  const float* cpg_w   = (const float*)d_in[3];
  const float* cpg_b   = (const float*)d_in[4];
  const float* ppg_w   = (const float*)d_in[5];
  const float* ppg_b   = (const float*)d_in[6];
  const float* ml      = (const float*)d_in[7];
  const float* mr      = (const float*)d_in[8];
  const float* sl      = (const float*)d_in[9];
  const float* sr      = (const float*)d_in[10];
  const float* base_w  = (const float*)d_in[11];
  const float* lora_A  = (const float*)d_in[12];
  const float* lora_B  = (const float*)d_in[13];
  const float* out_bias= (const float*)d_in[14];
  const float* gamma   = (const float*)d_in[15];
  const float* beta    = (const float*)d_in[16];
  float* out = (float*)d_out;

  float* wsf = (float*)d_ws;
  // ws layout (float offsets):
  bf16*  Wb       = (bf16*)(wsf + 0);           // 256x32768 bf16 =  4,194,304 f
  bf16*  cpg_wbp  = (bf16*)(wsf + 4194304);     // 32768x256 bf16 (perm) = 4,194,304 f
  float* cpg_bp   = wsf + 8388608;              // 32768 f
  bf16*  ppg_wb   = (bf16*)(wsf + 8421376);     // 512x256 bf16   =     65,536 f
  bf16*  qb       = (bf16*)(wsf + 8486912);     // 2400x256 bf16  =    307,200 f
  float* privb    = wsf + 8794112;              // 2400x512 f32   =  1,228,800 f
  bf16*  commonb  = (bf16*)(wsf + 10022912);    // 600x32768 bf16 =  9,830,400 f (also out2, in place)
  float* sharedbl = wsf + 19853312;             // union: partial 32x600x256 f32 = 4,915,200 f
  float* partialb = sharedbl;                   //        / xb chunk 600x8192 bf16 = 2,457,600 f
  bf16*  xbc      = (bf16*)sharedbl;            // (chain reads xbc before gemm2 overwrites as partial)
  // total = 24,768,512 floats = 99.1 MB

  // prep (once per call)
  cast_perm_k<<<dim3(FLAT / 8), 256, 0, stream>>>(cpg_w, cpg_wbp);
  perm_bias_k<<<dim3(FLAT / 256), 256, 0, stream>>>(cpg_b, cpg_bp);
  cast_k<<<dim3(512 * QDIM / 4 / 256), 256, 0, stream>>>(ppg_w, ppg_wb, 512 * QDIM / 4);
  cast_k<<<dim3(BN_TOK * QDIM / 4 / 256), 256, 0, stream>>>(query, qb, BN_TOK * QDIM / 4);
  build_wb_k<<<dim3(FLAT / 256, QDIM / 16), 256, 0, stream>>>(base_w, lora_A, lora_B, Wb);
  gemm_nt<false><<<dim3((BN_TOK + 127) / 128, 512 / 128), 256, 0, stream>>>(
      qb, ppg_wb, ppg_b, privb, BN_TOK, QDIM, 512);

  for (int ch = 0; ch < NCH; ++ch) {
    int t0 = ch * CT;
    // x chunk -> bf16 (aliases partial; dead after chain_k)
    cast_k<<<dim3(CT * GSZ / 4 / 256), 256, 0, stream>>>(
        x + (size_t)t0 * GSZ, xbc, CT * GSZ / 4);
    gemm_nt<true><<<dim3((CT + 127) / 128, FLAT / 128), 256, 0, stream>>>(
        qb + (size_t)t0 * QDIM, cpg_wbp, cpg_bp, commonb, CT, QDIM, FLAT);
    chain_k<<<dim3(CT, NG), 256, 0, stream>>>(xbc, privb, ml, mr, sl, sr, commonb, t0);
    gemm2_mfma<<<dim3((CT + 127) / 128, QDIM / 128, KSP), 256, 0, stream>>>(commonb, Wb, partialb);
    finish_k<<<dim3(CT), 256, 0, stream>>>(partialb, query, out_bias, gamma, beta, out, t0);
  }
}

// Round 6
// 402.488 us; speedup vs baseline: 1.2002x; 1.2002x over previous
//
#include <hip/hip_runtime.h>
#include <hip/hip_bf16.h>

// Problem constants
#define BN_TOK 2400     // B*N = 8*300
#define QDIM   256
#define NG     4
#define FLAT   32768    // G * (EOUT*POUT) = 4*8192
#define GSZ    8192
#define KSP    16       // split-K ways for gemm2
#define LN_EPS 1e-5f
#define PPAD   42       // row stride (ushorts) for [*][32-p] tiles: 21 dwords, odd -> conflict-free

typedef __attribute__((ext_vector_type(8))) short bf16x8;
typedef __attribute__((ext_vector_type(4))) float f32x4;
typedef __hip_bfloat16 bf16;

__device__ __forceinline__ float bf2f(ushort u) {
  union { unsigned int i; float f; } c;
  c.i = ((unsigned int)u) << 16;
  return c.f;
}
__device__ __forceinline__ ushort f2u(float f) {
  bf16 h = __float2bfloat16(f);
  union { bf16 h; ushort u; } c; c.h = h; return c.u;
}

// ---------------------------------------------------------------- fp32 -> bf16 cast
__global__ __launch_bounds__(256) void cast_k(const float* __restrict__ in,
                                              bf16* __restrict__ out, int n4) {
  int i = blockIdx.x * 256 + threadIdx.x;
  if (i < n4) {
    float4 v = ((const float4*)in)[i];
    bf16 tmp[4] = {__float2bfloat16(v.x), __float2bfloat16(v.y),
                   __float2bfloat16(v.z), __float2bfloat16(v.w)};
    ((ushort4*)out)[i] = *(const ushort4*)tmp;
  }
}

// ---------------------------------------------------------------- permuted cast of cpg_w:
// out row (g*8192 + d*64 + c) = in row (g*8192 + c*64 + d) for first 4096 of each group; rest copied.
__global__ __launch_bounds__(256) void cast_perm_k(const float* __restrict__ in,
                                                   bf16* __restrict__ out) {
  int tid = threadIdx.x;
  int orow = blockIdx.x * 8 + (tid >> 5);
  int g = orow >> 13, nl = orow & 8191;
  int srow = (nl < 4096) ? (g << 13) + ((nl & 63) << 6) + (nl >> 6) : orow;
  int col = (tid & 31) * 8;
  const float4* src = (const float4*)(in + (size_t)srow * QDIM + col);
  float4 a = src[0], b = src[1];
  bf16 tmp[8] = {__float2bfloat16(a.x), __float2bfloat16(a.y),
                 __float2bfloat16(a.z), __float2bfloat16(a.w),
                 __float2bfloat16(b.x), __float2bfloat16(b.y),
                 __float2bfloat16(b.z), __float2bfloat16(b.w)};
  *(bf16x8*)(out + (size_t)orow * QDIM + col) = *(const bf16x8*)tmp;
}

__global__ __launch_bounds__(256) void perm_bias_k(const float* __restrict__ in,
                                                   float* __restrict__ out) {
  int i = blockIdx.x * 256 + threadIdx.x;  // i < FLAT
  int g = i >> 13, nl = i & 8191;
  int src = (nl < 4096) ? (g << 13) + ((nl & 63) << 6) + (nl >> 6) : i;
  out[i] = in[src];
}

// ---------------------------------------------------------------- W = base_w + lora_B@lora_A (bf16, row-major [QDIM][FLAT])
__global__ __launch_bounds__(256) void build_wb_k(
    const float* __restrict__ base_w, const float* __restrict__ lora_A,
    const float* __restrict__ lora_B, bf16* __restrict__ Wb) {
  int jb = blockIdx.x * 256;
  int i0 = blockIdx.y * 16;
  int tid = threadIdx.x;
  __shared__ float lB[16][64];
  for (int e = tid; e < 16 * 64; e += 256)
    lB[e >> 6][e & 63] = lora_B[(size_t)(i0 + (e >> 6)) * 64 + (e & 63)];
  __syncthreads();
  int j = jb + tid;
  float acc[16] = {};
  for (int r = 0; r < 64; ++r) {
    float la = lora_A[(size_t)r * FLAT + j];
#pragma unroll
    for (int i = 0; i < 16; ++i) acc[i] += lB[i][r] * la;
  }
#pragma unroll
  for (int i = 0; i < 16; ++i)
    Wb[(size_t)(i0 + i) * FLAT + j] =
        __float2bfloat16(base_w[(size_t)(i0 + i) * FLAT + j] + acc[i]);
}

// ---------------------------------------------------------------- unified MFMA GEMM: C = A @ B^T (+bias)
// BK=64 with XOR swizzle (slot ^= row&7) on BOTH stage-source and ds_read side
// -> conflict-free fragment reads, half the barriers of BK=32.
// A [M][lda] bf16 (rows clamped), B [N][ldb] bf16; split-K via blockIdx.z (Kslice each).
// Cout row = blockIdx.z*M + row. bias may be null.
template <bool OBF>
__global__ __launch_bounds__(256) void gemm_nt(
    const bf16* __restrict__ A, const bf16* __restrict__ B,
    const float* __restrict__ bias, void* __restrict__ Cout,
    int M, int lda, int ldb, int Kslice, int ldc) {
  __shared__ ushort As[128 * 64];  // 16 KB
  __shared__ ushort Bs[128 * 64];  // 16 KB
  int tid = threadIdx.x;
  int w = tid >> 6, lane = tid & 63;
  int m0 = blockIdx.x * 128, n0 = blockIdx.y * 128;
  int kbase = blockIdx.z * Kslice;
  int wm = (w & 1) * 64, wn = (w >> 1) * 64;
  f32x4 acc[4][4] = {};
  for (int kb = 0; kb < Kslice; kb += 64) {
#pragma unroll
    for (int i = 0; i < 4; ++i) {
      int c = (i * 4 + w) * 64 + lane;   // 0..1023, 16B chunks, lane-contiguous dest
      int row = c >> 3, slot = c & 7;
      int ss = slot ^ (row & 7);         // pre-swizzled global source
      int grow = m0 + row; if (grow >= M) grow = M - 1;
      const bf16* src = A + (size_t)grow * lda + kbase + kb + ss * 8;
      __builtin_amdgcn_global_load_lds(
          (const __attribute__((address_space(1))) void*)src,
          (__attribute__((address_space(3))) void*)(As + (size_t)c * 8), 16, 0, 0);
    }
#pragma unroll
    for (int i = 0; i < 4; ++i) {
      int c = (i * 4 + w) * 64 + lane;
      int row = c >> 3, slot = c & 7;
      int ss = slot ^ (row & 7);
      const bf16* src = B + (size_t)(n0 + row) * ldb + kbase + kb + ss * 8;
      __builtin_amdgcn_global_load_lds(
          (const __attribute__((address_space(1))) void*)src,
          (__attribute__((address_space(3))) void*)(Bs + (size_t)c * 8), 16, 0, 0);
    }
    __syncthreads();
#pragma unroll
    for (int ks = 0; ks < 2; ++ks) {
      int sl = ks * 4 + (lane >> 4);  // logical 8-elem k-slot
      bf16x8 af[4], bfr[4];
#pragma unroll
      for (int i = 0; i < 4; ++i) {
        int r = wm + i * 16 + (lane & 15);
        af[i] = *(const bf16x8*)&As[r * 64 + (sl ^ (r & 7)) * 8];
        int cc = wn + i * 16 + (lane & 15);
        bfr[i] = *(const bf16x8*)&Bs[cc * 64 + (sl ^ (cc & 7)) * 8];
      }
#pragma unroll
      for (int i = 0; i < 4; ++i)
#pragma unroll
        for (int j = 0; j < 4; ++j)
          acc[i][j] = __builtin_amdgcn_mfma_f32_16x16x32_bf16(af[i], bfr[j], acc[i][j], 0, 0, 0);
    }
    __syncthreads();
  }
#pragma unroll
  for (int i = 0; i < 4; ++i) {
    int rb = m0 + wm + i * 16 + (lane >> 4) * 4;
#pragma unroll
    for (int j = 0; j < 4; ++j) {
      int col = n0 + wn + j * 16 + (lane & 15);
      float b = bias ? bias[col] : 0.f;
#pragma unroll
      for (int r = 0; r < 4; ++r) {
        if (rb + r < M) {
          size_t ro = (size_t)blockIdx.z * M + rb + r;
          float v = acc[i][j][r] + b;
          if (OBF)
            ((bf16*)Cout)[ro * ldc + col] = __float2bfloat16(v);
          else
            ((float*)Cout)[ro * ldc + col] = v;
        }
      }
    }
  }
}

// ---------------------------------------------------------------- chain (direct-fragment global reads)
__device__ __forceinline__ void block_red2(float& s, float& sq, float* redS,
                                           float* redQ, int tid) {
#pragma unroll
  for (int off = 32; off > 0; off >>= 1) {
    s += __shfl_down(s, off);
    sq += __shfl_down(sq, off);
  }
  int w = tid >> 6;
  if ((tid & 63) == 0) { redS[w] = s; redQ[w] = sq; }
  __syncthreads();
  s = redS[0] + redS[1] + redS[2] + redS[3];
  sq = redQ[0] + redQ[1] + redQ[2] + redQ[3];
}

__global__ __launch_bounds__(256) void chain_k(
    const bf16* __restrict__ xb, const float* __restrict__ priv,
    const float* __restrict__ ml, const float* __restrict__ mr,
    const float* __restrict__ sl, const float* __restrict__ sr,
    bf16* __restrict__ common, int t0) {
  int tid = threadIdx.x;
  int tl = blockIdx.x;
  int g = blockIdx.y;
  int t = t0 + tl;
  int lane = tid & 63, w = tid >> 6;

  __shared__ float mzs[64], szs[64];
  __shared__ float Am[64][8];
  __shared__ float Aso[128][8];
  __shared__ float srs[8][32];
  __shared__ ushort o1Tb[64 * PPAD];
  __shared__ float redS[4], redQ[4];

  if (tid < 64) mzs[tid] = priv[(size_t)t * 512 + g * 64 + tid];
  else if (tid < 128) szs[tid - 64] = priv[(size_t)t * 512 + 256 + g * 64 + (tid - 64)];
  srs[tid >> 5][tid & 31] = sr[g * 256 + tid];
  __syncthreads();

  for (int e = tid; e < 512; e += 256) {
    int c = e >> 3, l = e & 7;
    float s = 0.f;
#pragma unroll
    for (int k = 0; k < 8; ++k) s += ml[g * 512 + c * 8 + k] * mzs[k * 8 + l];
    Am[c][l] = s;
  }
  for (int e = tid; e < 1024; e += 256) {
    int o = e >> 3, l = e & 7;
    float s = 0.f;
#pragma unroll
    for (int k = 0; k < 8; ++k) s += sl[g * 1024 + o * 8 + k] * szs[k * 8 + l];
    Aso[o][l] = s;
  }
  __syncthreads();

  bf16* cm = common + (size_t)tl * FLAT + g * GSZ;
  const ushort* cmu = (const ushort*)cm;

  int dlane = w * 16 + (lane & 15);
  float mrv[8];
#pragma unroll
  for (int l = 0; l < 8; ++l) mrv[l] = mr[g * 512 + l * 64 + dlane];
  bf16x8 af[2];
#pragma unroll
  for (int ks = 0; ks < 2; ++ks) {
    bf16x8 mc = *(const bf16x8*)&cmu[dlane * 64 + ks * 32 + (lane >> 4) * 8];
#pragma unroll
    for (int j = 0; j < 8; ++j) {
      int c = ks * 32 + (lane >> 4) * 8 + j;
      float mp = 0.f;
#pragma unroll
      for (int l = 0; l < 8; ++l) mp += Am[c][l] * mrv[l];
      af[ks][j] = (short)f2u(bf2f((ushort)mc[j]) + mp);
    }
  }
  const ushort* xgu = (const ushort*)(xb + ((size_t)tl * NG + g) * 2048);
  f32x4 a1[2] = {};
#pragma unroll
  for (int ks = 0; ks < 2; ++ks) {
#pragma unroll
    for (int pt = 0; pt < 2; ++pt) {
      bf16x8 bx = *(const bf16x8*)&xgu[(pt * 16 + (lane & 15)) * 64 + ks * 32 + (lane >> 4) * 8];
      a1[pt] = __builtin_amdgcn_mfma_f32_16x16x32_bf16(af[ks], bx, a1[pt], 0, 0, 0);
    }
  }
  {
    float s = 0.f, sq = 0.f;
#pragma unroll
    for (int pt = 0; pt < 2; ++pt)
#pragma unroll
      for (int r = 0; r < 4; ++r) { float v = a1[pt][r]; s += v; sq += v * v; }
    block_red2(s, sq, redS, redQ, tid);
    float mean = s * (1.f / 2048.f);
    float var = sq * (1.f / 2048.f) - mean * mean;
    float rs = rsqrtf(var + LN_EPS);
#pragma unroll
    for (int pt = 0; pt < 2; ++pt)
#pragma unroll
      for (int r = 0; r < 4; ++r) {
        float v = (a1[pt][r] - mean) * rs;
        if (v < 0.f) v = 0.f;
        int d = w * 16 + (lane >> 4) * 4 + r;
        int p = pt * 16 + (lane & 15);
        o1Tb[d * PPAD + p] = f2u(v);
      }
  }
  __syncthreads();

  f32x4 a2[2][4] = {};
  {
    bf16x8 bfd[4];
#pragma unroll
    for (int dj = 0; dj < 4; ++dj)
      bfd[dj] = *(const bf16x8*)&o1Tb[(dj * 16 + (lane & 15)) * PPAD + (lane >> 4) * 8];
#pragma unroll
    for (int oi = 0; oi < 2; ++oi) {
      int o = (2 * w + oi) * 16 + (lane & 15);
      bf16x8 sc = *(const bf16x8*)&cmu[4096 + o * 32 + (lane >> 4) * 8];
      float asv[8];
#pragma unroll
      for (int l = 0; l < 8; ++l) asv[l] = Aso[o][l];
      bf16x8 sf;
#pragma unroll
      for (int j = 0; j < 8; ++j) {
        int p = (lane >> 4) * 8 + j;
        float sp = 0.f;
#pragma unroll
        for (int l = 0; l < 8; ++l) sp += asv[l] * srs[l][p];
        sf[j] = (short)f2u(bf2f((ushort)sc[j]) + sp);
      }
#pragma unroll
      for (int dj = 0; dj < 4; ++dj)
        a2[oi][dj] = __builtin_amdgcn_mfma_f32_16x16x32_bf16(sf, bfd[dj], a2[oi][dj], 0, 0, 0);
    }
  }
  {
    float s = 0.f, sq = 0.f;
#pragma unroll
    for (int oi = 0; oi < 2; ++oi)
#pragma unroll
      for (int dj = 0; dj < 4; ++dj)
#pragma unroll
        for (int r = 0; r < 4; ++r) { float v = a2[oi][dj][r]; s += v; sq += v * v; }
    block_red2(s, sq, redS, redQ, tid);
    float mean = s * (1.f / 8192.f);
    float var = sq * (1.f / 8192.f) - mean * mean;
    float rs = rsqrtf(var + LN_EPS);
#pragma unroll
    for (int oi = 0; oi < 2; ++oi)
#pragma unroll
      for (int dj = 0; dj < 4; ++dj)
#pragma unroll
        for (int r = 0; r < 4; ++r) {
          float v = (a2[oi][dj][r] - mean) * rs;
          if (v < 0.f) v = 0.f;
          int o = (2 * w + oi) * 16 + (lane >> 4) * 4 + r;
          int d = dj * 16 + (lane & 15);
          cm[o * 64 + d] = __float2bfloat16(v);
        }
  }
}

// ---------------------------------------------------------------- finish: reduce split-K + bias + residual + LN
__global__ __launch_bounds__(256) void finish_k(
    const float* __restrict__ partial, const float* __restrict__ query,
    const float* __restrict__ out_bias, const float* __restrict__ gamma,
    const float* __restrict__ beta, float* __restrict__ out, int t0, int M) {
  int tid = threadIdx.x;
  int tl = blockIdx.x;
  int t = t0 + tl;
  __shared__ float redS[4], redQ[4];
  float s = 0.f;
  for (int ks = 0; ks < KSP; ++ks)
    s += partial[((size_t)ks * M + tl) * QDIM + tid];
  float v = s + out_bias[tid] + query[(size_t)t * QDIM + tid];
  float sum = v, sqv = v * v;
  block_red2(sum, sqv, redS, redQ, tid);
  float mean = sum * (1.f / 256.f);
  float var = sqv * (1.f / 256.f) - mean * mean;
  out[(size_t)t * QDIM + tid] =
      (v - mean) * rsqrtf(var + LN_EPS) * gamma[tid] + beta[tid];
}

// ---------------------------------------------------------------- launch
extern "C" void kernel_launch(void* const* d_in, const int* in_sizes, int n_in,
                              void* d_out, int out_size, void* d_ws, size_t ws_size,
                              hipStream_t stream) {
  const float* x       = (const float*)d_in[1];
  const float* query   = (const float*)d_in[2];
  const float* cpg_w   = (const float*)d_in[3];
  const float* cpg_b   = (const float*)d_in[4];
  const float* ppg_w   = (const float*)d_in[5];
  const float* ppg_b   = (const float*)d_in[6];
  const float* ml      = (const float*)d_in[7];
  const float* mr      = (const float*)d_in[8];
  const float* sl      = (const float*)d_in[9];
  const float* sr      = (const float*)d_in[10];
  const float* base_w  = (const float*)d_in[11];
  const float* lora_A  = (const float*)d_in[12];
  const float* lora_B  = (const float*)d_in[13];
  const float* out_bias= (const float*)d_in[14];
  const float* gamma   = (const float*)d_in[15];
  const float* beta    = (const float*)d_in[16];
  float* out = (float*)d_out;

  float* wsf = (float*)d_ws;
  // fixed region (float offsets)
  bf16*  Wb       = (bf16*)(wsf + 0);           // 256x32768 bf16 = 4,194,304 f
  bf16*  cpg_wbp  = (bf16*)(wsf + 4194304);     // 32768x256 bf16 (perm) = 4,194,304 f
  float* cpg_bp   = wsf + 8388608;              // 32,768 f
  bf16*  ppg_wb   = (bf16*)(wsf + 8421376);     // 512x256 bf16 = 65,536 f
  bf16*  qb       = (bf16*)(wsf + 8486912);     // 2400x256 bf16 = 307,200 f
  float* privb    = wsf + 8794112;              // 2400x512 f32 = 1,228,800 f
  // dynamic region: commonb (CT*16384 f) + union (CT*4096 f: xb bf16 == partial f32)
  // full-batch need: 10,022,912 + 2400*20480 = 59,174,912 f = 236.7 MB

  size_t fixedF = 10022912;
  int CT = (ws_size >= (fixedF + (size_t)BN_TOK * 20480) * sizeof(float)) ? BN_TOK : 600;
  int NCH = BN_TOK / CT;
  bf16*  commonb = (bf16*)(wsf + fixedF);
  float* unionb  = wsf + fixedF + (size_t)CT * 16384;
  bf16*  xbc     = (bf16*)unionb;               // CT*8192 bf16  (dead after chain_k)
  float* partialb= unionb;                      // KSP*CT*256 f32 (written by gemm2)

  // prep (once per call)
  cast_perm_k<<<dim3(FLAT / 8), 256, 0, stream>>>(cpg_w, cpg_wbp);
  perm_bias_k<<<dim3(FLAT / 256), 256, 0, stream>>>(cpg_b, cpg_bp);
  cast_k<<<dim3(512 * QDIM / 4 / 256), 256, 0, stream>>>(ppg_w, ppg_wb, 512 * QDIM / 4);
  cast_k<<<dim3(BN_TOK * QDIM / 4 / 256), 256, 0, stream>>>(query, qb, BN_TOK * QDIM / 4);
  build_wb_k<<<dim3(FLAT / 256, QDIM / 16), 256, 0, stream>>>(base_w, lora_A, lora_B, Wb);
  // priv = qb @ ppg_wb^T + ppg_b  (M=2400, N=512, K=256)
  gemm_nt<false><<<dim3((BN_TOK + 127) / 128, 512 / 128, 1), 256, 0, stream>>>(
      qb, ppg_wb, ppg_b, privb, BN_TOK, QDIM, QDIM, QDIM, 512);

  for (int ch = 0; ch < NCH; ++ch) {
    int t0 = ch * CT;
    // x chunk -> bf16 (aliases partial; dead after chain_k)
    cast_k<<<dim3(CT * GSZ / 4 / 256), 256, 0, stream>>>(
        x + (size_t)t0 * GSZ, xbc, CT * GSZ / 4);
    // common = qb @ cpg_wbp^T + cpg_bp  (M=CT, N=32768, bf16 out)
    gemm_nt<true><<<dim3((CT + 127) / 128, FLAT / 128, 1), 256, 0, stream>>>(
        qb + (size_t)t0 * QDIM, cpg_wbp, cpg_bp, commonb, CT, QDIM, QDIM, QDIM, FLAT);
    chain_k<<<dim3(CT, NG), 256, 0, stream>>>(xbc, privb, ml, mr, sl, sr, commonb, t0);
    // partial[kz] = common @ Wb^T (K-slice of 32768/KSP)
    gemm_nt<false><<<dim3((CT + 127) / 128, QDIM / 128, KSP), 256, 0, stream>>>(
        commonb, Wb, nullptr, partialb, CT, FLAT, FLAT, FLAT / KSP, QDIM);
    finish_k<<<dim3(CT), 256, 0, stream>>>(partialb, query, out_bias, gamma, beta, out, t0, CT);
  }
}

// Round 7
// 371.464 us; speedup vs baseline: 1.3004x; 1.0835x over previous
//
#include <hip/hip_runtime.h>
#include <hip/hip_bf16.h>

// Problem constants
#define BN_TOK 2400     // B*N = 8*300
#define QDIM   256
#define NG     4
#define FLAT   32768    // G * (EOUT*POUT) = 4*8192
#define GSZ    8192
#define KSP    16       // split-K ways for gemm2
#define LN_EPS 1e-5f
#define PPAD   42       // row stride (ushorts) for [*][32-p] tiles: 21 dwords, odd -> conflict-free

typedef __attribute__((ext_vector_type(8))) short bf16x8;
typedef __attribute__((ext_vector_type(4))) float f32x4;
typedef __hip_bfloat16 bf16;

__device__ __forceinline__ float bf2f(ushort u) {
  union { unsigned int i; float f; } c;
  c.i = ((unsigned int)u) << 16;
  return c.f;
}
__device__ __forceinline__ ushort f2u(float f) {
  bf16 h = __float2bfloat16(f);
  union { bf16 h; ushort u; } c; c.h = h; return c.u;
}

// bijective XCD-chunked swizzle (m204): each of 8 XCDs gets a contiguous chunk
__device__ __forceinline__ int xcdswz(int orig, int nwg) {
  int xcd = orig & 7, base = orig >> 3;
  int q = nwg >> 3, r = nwg & 7;
  int start = (xcd < r) ? xcd * (q + 1) : r * (q + 1) + (xcd - r) * q;
  return start + base;
}

// ---------------------------------------------------------------- fp32 -> bf16 cast
__global__ __launch_bounds__(256) void cast_k(const float* __restrict__ in,
                                              bf16* __restrict__ out, int n4) {
  int i = blockIdx.x * 256 + threadIdx.x;
  if (i < n4) {
    float4 v = ((const float4*)in)[i];
    bf16 tmp[4] = {__float2bfloat16(v.x), __float2bfloat16(v.y),
                   __float2bfloat16(v.z), __float2bfloat16(v.w)};
    ((ushort4*)out)[i] = *(const ushort4*)tmp;
  }
}

// ---------------------------------------------------------------- permuted cast of cpg_w
__global__ __launch_bounds__(256) void cast_perm_k(const float* __restrict__ in,
                                                   bf16* __restrict__ out) {
  int tid = threadIdx.x;
  int orow = blockIdx.x * 8 + (tid >> 5);
  int g = orow >> 13, nl = orow & 8191;
  int srow = (nl < 4096) ? (g << 13) + ((nl & 63) << 6) + (nl >> 6) : orow;
  int col = (tid & 31) * 8;
  const float4* src = (const float4*)(in + (size_t)srow * QDIM + col);
  float4 a = src[0], b = src[1];
  bf16 tmp[8] = {__float2bfloat16(a.x), __float2bfloat16(a.y),
                 __float2bfloat16(a.z), __float2bfloat16(a.w),
                 __float2bfloat16(b.x), __float2bfloat16(b.y),
                 __float2bfloat16(b.z), __float2bfloat16(b.w)};
  *(bf16x8*)(out + (size_t)orow * QDIM + col) = *(const bf16x8*)tmp;
}

__global__ __launch_bounds__(256) void perm_bias_k(const float* __restrict__ in,
                                                   float* __restrict__ out) {
  int i = blockIdx.x * 256 + threadIdx.x;
  int g = i >> 13, nl = i & 8191;
  int src = (nl < 4096) ? (g << 13) + ((nl & 63) << 6) + (nl >> 6) : i;
  out[i] = in[src];
}

// ---------------------------------------------------------------- W = base_w + lora_B@lora_A
__global__ __launch_bounds__(256) void build_wb_k(
    const float* __restrict__ base_w, const float* __restrict__ lora_A,
    const float* __restrict__ lora_B, bf16* __restrict__ Wb) {
  int jb = blockIdx.x * 256;
  int i0 = blockIdx.y * 16;
  int tid = threadIdx.x;
  __shared__ float lB[16][64];
  for (int e = tid; e < 16 * 64; e += 256)
    lB[e >> 6][e & 63] = lora_B[(size_t)(i0 + (e >> 6)) * 64 + (e & 63)];
  __syncthreads();
  int j = jb + tid;
  float acc[16] = {};
  for (int r = 0; r < 64; ++r) {
    float la = lora_A[(size_t)r * FLAT + j];
#pragma unroll
    for (int i = 0; i < 16; ++i) acc[i] += lB[i][r] * la;
  }
#pragma unroll
  for (int i = 0; i < 16; ++i)
    Wb[(size_t)(i0 + i) * FLAT + j] =
        __float2bfloat16(base_w[(size_t)(i0 + i) * FLAT + j] + acc[i]);
}

// ---------------------------------------------------------------- unified MFMA GEMM: C = A @ B^T (+bias)
// Operand-swapped MFMA (D rows = n) -> thread owns 4 consecutive n -> vectorized stores.
// BK=64, both-sides XOR swizzle; XCD-chunked block swizzle; split-K via blockIdx.z.
template <bool OBF>
__global__ __launch_bounds__(256) void gemm_nt(
    const bf16* __restrict__ A, const bf16* __restrict__ B,
    const float* __restrict__ bias, void* __restrict__ Cout,
    int M, int lda, int ldb, int Kslice, int ldc) {
  __shared__ ushort As[128 * 64];  // 16 KB
  __shared__ ushort Bs[128 * 64];  // 16 KB
  int tid = threadIdx.x;
  int w = tid >> 6, lane = tid & 63;
  int nwg = gridDim.x * gridDim.y;
  int swz = xcdswz(blockIdx.x + gridDim.x * blockIdx.y, nwg);
  int m0 = (swz % gridDim.x) * 128, n0 = (swz / gridDim.x) * 128;
  int kbase = blockIdx.z * Kslice;
  int wm = (w & 1) * 64, wn = (w >> 1) * 64;
  f32x4 acc[4][4] = {};
  for (int kb = 0; kb < Kslice; kb += 64) {
#pragma unroll
    for (int i = 0; i < 4; ++i) {
      int c = (i * 4 + w) * 64 + lane;   // 0..1023, 16B chunks
      int row = c >> 3, slot = c & 7;
      int ss = slot ^ (row & 7);         // pre-swizzled global source
      int grow = m0 + row; if (grow >= M) grow = M - 1;
      const bf16* src = A + (size_t)grow * lda + kbase + kb + ss * 8;
      __builtin_amdgcn_global_load_lds(
          (const __attribute__((address_space(1))) void*)src,
          (__attribute__((address_space(3))) void*)(As + (size_t)c * 8), 16, 0, 0);
    }
#pragma unroll
    for (int i = 0; i < 4; ++i) {
      int c = (i * 4 + w) * 64 + lane;
      int row = c >> 3, slot = c & 7;
      int ss = slot ^ (row & 7);
      const bf16* src = B + (size_t)(n0 + row) * ldb + kbase + kb + ss * 8;
      __builtin_amdgcn_global_load_lds(
          (const __attribute__((address_space(1))) void*)src,
          (__attribute__((address_space(3))) void*)(Bs + (size_t)c * 8), 16, 0, 0);
    }
    __syncthreads();
#pragma unroll
    for (int ks = 0; ks < 2; ++ks) {
      int sl = ks * 4 + (lane >> 4);
      bf16x8 af[4], bfr[4];
#pragma unroll
      for (int i = 0; i < 4; ++i) {
        int r = wm + i * 16 + (lane & 15);
        af[i] = *(const bf16x8*)&As[r * 64 + (sl ^ (r & 7)) * 8];
        int cc = wn + i * 16 + (lane & 15);
        bfr[i] = *(const bf16x8*)&Bs[cc * 64 + (sl ^ (cc & 7)) * 8];
      }
#pragma unroll
      for (int i = 0; i < 4; ++i)
#pragma unroll
        for (int j = 0; j < 4; ++j)
          acc[i][j] = __builtin_amdgcn_mfma_f32_16x16x32_bf16(bfr[j], af[i], acc[i][j], 0, 0, 0);
    }
    __syncthreads();
  }
  // epilogue: thread owns (m fixed, 4 consecutive n) per (i,j)
#pragma unroll
  for (int i = 0; i < 4; ++i) {
    int m = m0 + wm + i * 16 + (lane & 15);
    if (m >= M) continue;
    size_t ro = (size_t)blockIdx.z * M + m;
#pragma unroll
    for (int j = 0; j < 4; ++j) {
      int nb = n0 + wn + j * 16 + (lane >> 4) * 4;
      float4 b4 = bias ? *(const float4*)&bias[nb] : make_float4(0.f, 0.f, 0.f, 0.f);
      float v0 = acc[i][j][0] + b4.x, v1 = acc[i][j][1] + b4.y;
      float v2 = acc[i][j][2] + b4.z, v3 = acc[i][j][3] + b4.w;
      if (OBF) {
        ushort4 uv = {f2u(v0), f2u(v1), f2u(v2), f2u(v3)};
        *(ushort4*)((bf16*)Cout + ro * ldc + nb) = uv;
      } else {
        *(float4*)((float*)Cout + ro * ldc + nb) = make_float4(v0, v1, v2, v3);
      }
    }
  }
}

// ---------------------------------------------------------------- chain (direct-fragment reads, fp32 x)
__device__ __forceinline__ void block_red2(float& s, float& sq, float* redS,
                                           float* redQ, int tid) {
#pragma unroll
  for (int off = 32; off > 0; off >>= 1) {
    s += __shfl_down(s, off);
    sq += __shfl_down(sq, off);
  }
  int w = tid >> 6;
  if ((tid & 63) == 0) { redS[w] = s; redQ[w] = sq; }
  __syncthreads();
  s = redS[0] + redS[1] + redS[2] + redS[3];
  sq = redQ[0] + redQ[1] + redQ[2] + redQ[3];
}

__global__ __launch_bounds__(256) void chain_k(
    const float* __restrict__ x, const float* __restrict__ priv,
    const float* __restrict__ ml, const float* __restrict__ mr,
    const float* __restrict__ sl, const float* __restrict__ sr,
    bf16* __restrict__ common, int t0) {
  int tid = threadIdx.x;
  int tl = blockIdx.x;
  int g = blockIdx.y;
  int t = t0 + tl;
  int lane = tid & 63, w = tid >> 6;

  __shared__ float mzs[64], szs[64];
  __shared__ float Am[64][8];
  __shared__ float Aso[128][8];
  __shared__ float srs[8][32];
  __shared__ ushort o1Tb[64 * PPAD];
  __shared__ float redS[4], redQ[4];

  if (tid < 64) mzs[tid] = priv[(size_t)t * 512 + g * 64 + tid];
  else if (tid < 128) szs[tid - 64] = priv[(size_t)t * 512 + 256 + g * 64 + (tid - 64)];
  srs[tid >> 5][tid & 31] = sr[g * 256 + tid];
  __syncthreads();

  for (int e = tid; e < 512; e += 256) {
    int c = e >> 3, l = e & 7;
    float s = 0.f;
#pragma unroll
    for (int k = 0; k < 8; ++k) s += ml[g * 512 + c * 8 + k] * mzs[k * 8 + l];
    Am[c][l] = s;
  }
  for (int e = tid; e < 1024; e += 256) {
    int o = e >> 3, l = e & 7;
    float s = 0.f;
#pragma unroll
    for (int k = 0; k < 8; ++k) s += sl[g * 1024 + o * 8 + k] * szs[k * 8 + l];
    Aso[o][l] = s;
  }
  __syncthreads();

  bf16* cm = common + (size_t)tl * FLAT + g * GSZ;
  const ushort* cmu = (const ushort*)cm;

  // A-fragments of M^T: global b128 + in-register +Am@mr
  int dlane = w * 16 + (lane & 15);
  float mrv[8];
#pragma unroll
  for (int l = 0; l < 8; ++l) mrv[l] = mr[g * 512 + l * 64 + dlane];
  bf16x8 af[2];
#pragma unroll
  for (int ks = 0; ks < 2; ++ks) {
    bf16x8 mc = *(const bf16x8*)&cmu[dlane * 64 + ks * 32 + (lane >> 4) * 8];
#pragma unroll
    for (int j = 0; j < 8; ++j) {
      int c = ks * 32 + (lane >> 4) * 8 + j;
      float mp = 0.f;
#pragma unroll
      for (int l = 0; l < 8; ++l) mp += Am[c][l] * mrv[l];
      af[ks][j] = (short)f2u(bf2f((ushort)mc[j]) + mp);
    }
  }
  // B-fragments of x: fp32 global, packed in-register
  const float* xg = x + (size_t)t * GSZ + g * 2048;
  f32x4 a1[2] = {};
#pragma unroll
  for (int ks = 0; ks < 2; ++ks) {
#pragma unroll
    for (int pt = 0; pt < 2; ++pt) {
      int p = pt * 16 + (lane & 15);
      int k = ks * 32 + (lane >> 4) * 8;
      const float4* xp = (const float4*)(xg + p * 64 + k);
      float4 f0 = xp[0], f1 = xp[1];
      bf16x8 bx;
      bx[0] = (short)f2u(f0.x); bx[1] = (short)f2u(f0.y);
      bx[2] = (short)f2u(f0.z); bx[3] = (short)f2u(f0.w);
      bx[4] = (short)f2u(f1.x); bx[5] = (short)f2u(f1.y);
      bx[6] = (short)f2u(f1.z); bx[7] = (short)f2u(f1.w);
      a1[pt] = __builtin_amdgcn_mfma_f32_16x16x32_bf16(af[ks], bx, a1[pt], 0, 0, 0);
    }
  }
  // LN1 over 2048 + relu -> o1^T bf16 in LDS
  {
    float s = 0.f, sq = 0.f;
#pragma unroll
    for (int pt = 0; pt < 2; ++pt)
#pragma unroll
      for (int r = 0; r < 4; ++r) { float v = a1[pt][r]; s += v; sq += v * v; }
    block_red2(s, sq, redS, redQ, tid);
    float mean = s * (1.f / 2048.f);
    float var = sq * (1.f / 2048.f) - mean * mean;
    float rs = rsqrtf(var + LN_EPS);
#pragma unroll
    for (int pt = 0; pt < 2; ++pt)
#pragma unroll
      for (int r = 0; r < 4; ++r) {
        float v = (a1[pt][r] - mean) * rs;
        if (v < 0.f) v = 0.f;
        int d = w * 16 + (lane >> 4) * 4 + r;
        int p = pt * 16 + (lane & 15);
        o1Tb[d * PPAD + p] = f2u(v);
      }
  }
  __syncthreads();

  // out2 = S @ o1 via swapped mfma -> thread owns (o fixed, 4 consecutive d)
  f32x4 a2[2][4] = {};
  {
    bf16x8 bfd[4];
#pragma unroll
    for (int dj = 0; dj < 4; ++dj)
      bfd[dj] = *(const bf16x8*)&o1Tb[(dj * 16 + (lane & 15)) * PPAD + (lane >> 4) * 8];
#pragma unroll
    for (int oi = 0; oi < 2; ++oi) {
      int o = (2 * w + oi) * 16 + (lane & 15);
      bf16x8 sc = *(const bf16x8*)&cmu[4096 + o * 32 + (lane >> 4) * 8];
      float asv[8];
#pragma unroll
      for (int l = 0; l < 8; ++l) asv[l] = Aso[o][l];
      bf16x8 sf;
#pragma unroll
      for (int j = 0; j < 8; ++j) {
        int p = (lane >> 4) * 8 + j;
        float sp = 0.f;
#pragma unroll
        for (int l = 0; l < 8; ++l) sp += asv[l] * srs[l][p];
        sf[j] = (short)f2u(bf2f((ushort)sc[j]) + sp);
      }
#pragma unroll
      for (int dj = 0; dj < 4; ++dj)
        a2[oi][dj] = __builtin_amdgcn_mfma_f32_16x16x32_bf16(bfd[dj], sf, a2[oi][dj], 0, 0, 0);
    }
  }
  // LN2 over 8192 + relu -> vectorized bf16 write in place
  {
    float s = 0.f, sq = 0.f;
#pragma unroll
    for (int oi = 0; oi < 2; ++oi)
#pragma unroll
      for (int dj = 0; dj < 4; ++dj)
#pragma unroll
        for (int r = 0; r < 4; ++r) { float v = a2[oi][dj][r]; s += v; sq += v * v; }
    block_red2(s, sq, redS, redQ, tid);
    float mean = s * (1.f / 8192.f);
    float var = sq * (1.f / 8192.f) - mean * mean;
    float rs = rsqrtf(var + LN_EPS);
    ushort* cw = (ushort*)cm;
#pragma unroll
    for (int oi = 0; oi < 2; ++oi) {
      int o = (2 * w + oi) * 16 + (lane & 15);
#pragma unroll
      for (int dj = 0; dj < 4; ++dj) {
        int d0 = dj * 16 + (lane >> 4) * 4;
        ushort4 uv;
#pragma unroll
        for (int r = 0; r < 4; ++r) {
          float v = (a2[oi][dj][r] - mean) * rs;
          if (v < 0.f) v = 0.f;
          ((ushort*)&uv)[r] = f2u(v);
        }
        *(ushort4*)&cw[o * 64 + d0] = uv;
      }
    }
  }
}

// ---------------------------------------------------------------- finish
__global__ __launch_bounds__(256) void finish_k(
    const float* __restrict__ partial, const float* __restrict__ query,
    const float* __restrict__ out_bias, const float* __restrict__ gamma,
    const float* __restrict__ beta, float* __restrict__ out, int t0, int M) {
  int tid = threadIdx.x;
  int tl = blockIdx.x;
  int t = t0 + tl;
  __shared__ float redS[4], redQ[4];
  float s = 0.f;
  for (int ks = 0; ks < KSP; ++ks)
    s += partial[((size_t)ks * M + tl) * QDIM + tid];
  float v = s + out_bias[tid] + query[(size_t)t * QDIM + tid];
  float sum = v, sqv = v * v;
  block_red2(sum, sqv, redS, redQ, tid);
  float mean = sum * (1.f / 256.f);
  float var = sqv * (1.f / 256.f) - mean * mean;
  out[(size_t)t * QDIM + tid] =
      (v - mean) * rsqrtf(var + LN_EPS) * gamma[tid] + beta[tid];
}

// ---------------------------------------------------------------- launch
extern "C" void kernel_launch(void* const* d_in, const int* in_sizes, int n_in,
                              void* d_out, int out_size, void* d_ws, size_t ws_size,
                              hipStream_t stream) {
  const float* x       = (const float*)d_in[1];
  const float* query   = (const float*)d_in[2];
  const float* cpg_w   = (const float*)d_in[3];
  const float* cpg_b   = (const float*)d_in[4];
  const float* ppg_w   = (const float*)d_in[5];
  const float* ppg_b   = (const float*)d_in[6];
  const float* ml      = (const float*)d_in[7];
  const float* mr      = (const float*)d_in[8];
  const float* sl      = (const float*)d_in[9];
  const float* sr      = (const float*)d_in[10];
  const float* base_w  = (const float*)d_in[11];
  const float* lora_A  = (const float*)d_in[12];
  const float* lora_B  = (const float*)d_in[13];
  const float* out_bias= (const float*)d_in[14];
  const float* gamma   = (const float*)d_in[15];
  const float* beta    = (const float*)d_in[16];
  float* out = (float*)d_out;

  float* wsf = (float*)d_ws;
  // fixed region (float offsets)
  bf16*  Wb       = (bf16*)(wsf + 0);           // 256x32768 bf16 = 4,194,304 f
  bf16*  cpg_wbp  = (bf16*)(wsf + 4194304);     // 32768x256 bf16 (perm) = 4,194,304 f
  float* cpg_bp   = wsf + 8388608;              // 32,768 f
  bf16*  ppg_wb   = (bf16*)(wsf + 8421376);     // 512x256 bf16 = 65,536 f
  bf16*  qb       = (bf16*)(wsf + 8486912);     // 2400x256 bf16 = 307,200 f
  float* privb    = wsf + 8794112;              // 2400x512 f32 = 1,228,800 f
  size_t fixedF = 10022912;
  // dynamic: commonb CT*16384 f + partial KSP*CT*256 f = CT*20480 f
  int CT = (ws_size >= (fixedF + (size_t)BN_TOK * 20480) * sizeof(float)) ? BN_TOK : 600;
  int NCH = BN_TOK / CT;
  bf16*  commonb = (bf16*)(wsf + fixedF);
  float* partialb= wsf + fixedF + (size_t)CT * 16384;

  // prep (once per call)
  cast_perm_k<<<dim3(FLAT / 8), 256, 0, stream>>>(cpg_w, cpg_wbp);
  perm_bias_k<<<dim3(FLAT / 256), 256, 0, stream>>>(cpg_b, cpg_bp);
  cast_k<<<dim3(512 * QDIM / 4 / 256), 256, 0, stream>>>(ppg_w, ppg_wb, 512 * QDIM / 4);
  cast_k<<<dim3(BN_TOK * QDIM / 4 / 256), 256, 0, stream>>>(query, qb, BN_TOK * QDIM / 4);
  build_wb_k<<<dim3(FLAT / 256, QDIM / 16), 256, 0, stream>>>(base_w, lora_A, lora_B, Wb);
  // priv = qb @ ppg_wb^T + ppg_b
  gemm_nt<false><<<dim3((BN_TOK + 127) / 128, 512 / 128, 1), 256, 0, stream>>>(
      qb, ppg_wb, ppg_b, privb, BN_TOK, QDIM, QDIM, QDIM, 512);

  for (int ch = 0; ch < NCH; ++ch) {
    int t0 = ch * CT;
    // common = qb @ cpg_wbp^T + cpg_bp
    gemm_nt<true><<<dim3((CT + 127) / 128, FLAT / 128, 1), 256, 0, stream>>>(
        qb + (size_t)t0 * QDIM, cpg_wbp, cpg_bp, commonb, CT, QDIM, QDIM, QDIM, FLAT);
    chain_k<<<dim3(CT, NG), 256, 0, stream>>>(x + (size_t)t0 * GSZ, privb + (size_t)t0 * 512,
                                              ml, mr, sl, sr, commonb, 0);
    // partial[kz] = common @ Wb^T (K-slice)
    gemm_nt<false><<<dim3((CT + 127) / 128, QDIM / 128, KSP), 256, 0, stream>>>(
        commonb, Wb, nullptr, partialb, CT, FLAT, FLAT, FLAT / KSP, QDIM);
    finish_k<<<dim3(CT), 256, 0, stream>>>(partialb, query, out_bias, gamma, beta, out, t0, CT);
  }
}